// Round 10
// baseline (89.083 us; speedup 1.0000x reference)
//
#include <hip/hip_runtime.h>
#include <stdint.h>

// Problem constants: B=2, T=2048, C=1024, H=16, D=64
// GEMM1: [4096,1024] x [3072,1024]^T -> q,k,v  (128^2, dbuf+counted-vmcnt)
// attn : 32 heads, causal, T=2048, D=64
// GEMM2: [4096,1024] x [1024,1024]^T -> out (fp32), prefetch-dbuf, XCD-compact

typedef unsigned short u16;
typedef __bf16 bf16_t;
typedef bf16_t bf16x8 __attribute__((ext_vector_type(8)));
typedef float f32x4 __attribute__((ext_vector_type(4)));
typedef float f32x16 __attribute__((ext_vector_type(16)));

__device__ __forceinline__ u16 f2bf(float f) {
  return __builtin_bit_cast(u16, (bf16_t)f);   // RNE
}

__device__ __forceinline__ float hexp2(float x) {   // raw v_exp_f32 (log2 domain)
  float r;
  asm("v_exp_f32 %0, %1" : "=v"(r) : "v"(x));
  return r;
}
__device__ __forceinline__ uint32_t cvtpk(float lo, float hi) {
  uint32_t d;
  asm("v_cvt_pk_bf16_f32 %0, %1, %2" : "=v"(d) : "v"(lo), "v"(hi));
  return d;
}
__device__ __forceinline__ void plswap(uint32_t& a, uint32_t& b) {
  asm("v_permlane32_swap_b32 %0, %1" : "+v"(a), "+v"(b));
}

// PV A-fragment (k-chunk CC of 16 within a 32-k half) from this lane's 16 S^T
// values (k_local = (reg&3) + 8*(reg>>2) + 4*hi).
template<int CC>
__device__ __forceinline__ bf16x8 mkPfrag(const float* p) {
  uint32_t A1 = cvtpk(p[8 * CC + 0], p[8 * CC + 1]);
  uint32_t A2 = cvtpk(p[8 * CC + 2], p[8 * CC + 3]);
  uint32_t B1 = cvtpk(p[8 * CC + 4], p[8 * CC + 5]);
  uint32_t B2 = cvtpk(p[8 * CC + 6], p[8 * CC + 7]);
  plswap(A1, B1);
  plswap(A2, B2);
  union { uint32_t u[4]; bf16x8 v; } r;
  r.u[0] = A1; r.u[1] = A2; r.u[2] = B1; r.u[3] = B2;
  return r.v;
}

// global -> LDS direct copy, 16B per lane (linear LDS dest; swizzle on source).
__device__ __forceinline__ void gload_lds16(const void* g, void* l) {
  __builtin_amdgcn_global_load_lds(
      (const __attribute__((address_space(1))) uint32_t*)(uint64_t)g,
      (__attribute__((address_space(3))) uint32_t*)(uint32_t)(uint64_t)l,
      16, 0, 0);
}

// Fused bf16 cast of x, w_qkv, w_proj.
__global__ void cast_all(const float* __restrict__ x, const float* __restrict__ wq,
                         const float* __restrict__ wp, u16* __restrict__ xb,
                         u16* __restrict__ wqb, u16* __restrict__ wpb) {
  int i = blockIdx.x * blockDim.x + threadIdx.x;
  const float* s; u16* d; int off;
  if (i < 1048576)            { s = x;  d = xb;  off = i; }
  else if (i < 1048576 + 786432) { s = wq; d = wqb; off = i - 1048576; }
  else                        { s = wp; d = wpb; off = i - (1048576 + 786432); }
  float4 f = reinterpret_cast<const float4*>(s)[off];
  ushort4 o;
  o.x = f2bf(f.x); o.y = f2bf(f.y); o.z = f2bf(f.z); o.w = f2bf(f.w);
  reinterpret_cast<ushort4*>(d)[off] = o;
}

// ---------------------------------------------------------------------------
// GEMM1: 128x128 tile, BK=64, 256 threads (2x2 waves, 64x64/wave).
// Double-buffered LDS (2 x 32KB -> 2 blocks/CU): stage(t+1) issued before
// compute(t); counted s_waitcnt vmcnt(8) + raw s_barrier -- no vmcnt(0)
// drain in the loop (race-free: stage(t+2)->buf(t) is issued after the
// trailing barrier, by which point all reads of buf(t) completed).
// XCD-compact remap: XCD owns a 12(tn) x 8(tm) rectangle.
// Epilogue: ALL outputs via per-wave LDS transpose -> coalesced stores:
//   q*SC, k as [b,h,t,d] (128B t-rows), v as [b,h,d,t] (128B d-rows).
// ---------------------------------------------------------------------------
__global__ void gemm_qkv(const u16* __restrict__ A, const u16* __restrict__ Bm,
                         u16* __restrict__ qb, u16* __restrict__ kb,
                         u16* __restrict__ vb) {
  __shared__ __attribute__((aligned(16))) u16 SMEM[32768];   // 64KB: 2 bufs
  const int tid = threadIdx.x;
  const int lane = tid & 63;
  const int w = tid >> 6;
  const int wr = w >> 1, wc = w & 1;
  const int g = lane >> 4, r = lane & 15;
  // XCD-compact bijective remap: 768 blocks -> 8 rectangles of 12tn x 8tm.
  const int bid = blockIdx.x + 24 * blockIdx.y;
  const int xcd = bid & 7, idx = bid >> 3;           // idx 0..95
  const int tn = (xcd & 1) * 12 + (idx % 12);
  const int tm = (xcd >> 1) * 8 + (idx / 12);

  f32x4 acc[4][4] = {};

  const char* Ab = (const char*)(A + (size_t)tm * 128 * 1024);
  const char* Bb = (const char*)(Bm + (size_t)tn * 128 * 1024);

  auto stage = [&](int t, int buf) {
    char* AsD = (char*)SMEM + buf * 32768;
    char* BsD = AsD + 16384;
    const int k0b = t * 128;                 // byte offset along K
#pragma unroll
    for (int i = 0; i < 4; ++i) {
      const int L = (i * 256 + tid) * 16;
      const int row = L >> 7;
      const int colb = (L & 127) ^ ((row & 7) << 4);
      gload_lds16(Ab + (size_t)row * 2048 + k0b + colb, AsD + L);
      gload_lds16(Bb + (size_t)row * 2048 + k0b + colb, BsD + L);
    }
  };

  stage(0, 0);
  for (int t = 0; t < 16; ++t) {
    if (t < 15) {
      stage(t + 1, (t + 1) & 1);                       // 8 loads in flight
      asm volatile("s_waitcnt vmcnt(8)" ::: "memory"); // tile t landed
    } else {
      asm volatile("s_waitcnt vmcnt(0)" ::: "memory");
    }
    __builtin_amdgcn_s_barrier();
    __builtin_amdgcn_sched_barrier(0);
    const char* AsB = (const char*)SMEM + (t & 1) * 32768;
    const char* BsB = AsB + 16384;
#pragma unroll
    for (int kk = 0; kk < 2; ++kk) {
      bf16x8 a[4], b[4];
#pragma unroll
      for (int m = 0; m < 4; ++m) {
        const int rowA = wr * 64 + m * 16 + r;
        const int kbyt = (kk * 64 + g * 16) ^ ((rowA & 7) << 4);
        a[m] = *(const bf16x8*)(AsB + rowA * 128 + kbyt);
      }
#pragma unroll
      for (int n = 0; n < 4; ++n) {
        const int rowB = wc * 64 + n * 16 + r;
        const int kbyt = (kk * 64 + g * 16) ^ ((rowB & 7) << 4);
        b[n] = *(const bf16x8*)(BsB + rowB * 128 + kbyt);
      }
      __builtin_amdgcn_s_setprio(1);
#pragma unroll
      for (int m = 0; m < 4; ++m)
#pragma unroll
        for (int n = 0; n < 4; ++n)
          acc[m][n] = __builtin_amdgcn_mfma_f32_16x16x32_bf16(a[m], b[n], acc[m][n], 0, 0, 0);
      __builtin_amdgcn_s_setprio(0);
    }
    __builtin_amdgcn_sched_barrier(0);
    __builtin_amdgcn_s_barrier();              // all reads of buf(t&1) done
  }

  // ---- epilogue: per-wave 8KB LDS transpose buffers (reuse SMEM) ----------
  const int mrow0 = tm * 128 + wr * 64;
  const int ncol0 = tn * 128 + wc * 64;
  const int sel = (tn * 128) >> 10;
  u16* Wb = SMEM + w * 4096;                   // 8KB per wave (u16 index)

  if (sel < 2) {
    // q/k: build W[t][d] (64 x 64, 128B rows, 16B-granule XOR swizzle),
    // then store full 128B t-rows (8 lanes x 16B, coalesced).
    const float qscl = (sel == 0) ? 0.18033688f : 1.0f;  // 0.125*log2(e)
#pragma unroll
    for (int m = 0; m < 4; ++m)
#pragma unroll
      for (int n = 0; n < 4; ++n)
#pragma unroll
        for (int j = 0; j < 4; ++j) {
          const int tl = m * 16 + g * 4 + j;
          const int d = n * 16 + r;
          *(u16*)((char*)Wb + tl * 128 + ((d * 2) ^ ((tl & 7) << 4))) =
              f2bf(acc[m][n][j] * qscl);
        }
    asm volatile("s_waitcnt lgkmcnt(0)" ::: "memory");   // wave-local
    __builtin_amdgcn_sched_barrier(0);
    u16* dst = (sel == 0) ? qb : kb;
    const int h = (ncol0 & 1023) >> 6;
    const int bb = mrow0 >> 11, t0 = mrow0 & 2047;
    u16* drow = dst + ((size_t)(bb * 16 + h) * 2048 + t0) * 64;
#pragma unroll
    for (int it = 0; it < 8; ++it) {
      const int tl = it * 8 + (lane >> 3);
      const int cb = (lane & 7) * 16;
      const char* src = (char*)Wb + tl * 128 + (cb ^ ((tl & 7) << 4));
      *(uint4*)((char*)(drow + (size_t)tl * 64) + cb) = *(const uint4*)src;
    }
  } else {
    // v: [b,h,d,t] via W[d][t] transpose (b64 packed writes).
#pragma unroll
    for (int m = 0; m < 4; ++m)
#pragma unroll
      for (int n = 0; n < 4; ++n) {
        const int dl = n * 16 + r;
        uint32_t lo = cvtpk(acc[m][n][0], acc[m][n][1]);
        uint32_t hi2 = cvtpk(acc[m][n][2], acc[m][n][3]);
        char* p = (char*)Wb + dl * 128 + ((m * 32 + g * 8) ^ ((dl & 7) << 4));
        *(uint64_t*)p = ((uint64_t)hi2 << 32) | lo;
      }
    asm volatile("s_waitcnt lgkmcnt(0)" ::: "memory");   // wave-local
    __builtin_amdgcn_sched_barrier(0);
    const int hh = (ncol0 - 2048) >> 6;
    const int t0 = mrow0 & 2047;
    const int bb2 = mrow0 >> 11;
    u16* vdst = vb + ((size_t)(bb2 * 16 + hh) * 64) * 2048 + t0;
#pragma unroll
    for (int rd = 0; rd < 8; ++rd) {
      const int dl = rd * 8 + (lane >> 3);
      const int tb = lane & 7;
      const char* src = (char*)Wb + dl * 128 + ((tb ^ (dl & 7)) << 4);
      *(uint4*)(vdst + (size_t)dl * 2048 + tb * 8) = *(const uint4*)src;
    }
  }
}

// ---------------------------------------------------------------------------
// GEMM2: 64x128 tile, BK=64, 256 threads (1x4 waves, 64x32/wave), fp32 out.
// Prefetch double-buffer, counted vmcnt(6) + raw s_barrier.
// XCD-compact remap: XCD owns 2(tn) x 32(tm).
// ---------------------------------------------------------------------------
__global__ void gemm_out(const u16* __restrict__ A, const u16* __restrict__ Bm,
                         float* __restrict__ outf) {
  __shared__ __attribute__((aligned(16))) u16 SMEM[24576];   // 2 x 24KB
  const int tid = threadIdx.x;
  const int lane = tid & 63;
  const int w = tid >> 6;
  const int g = lane >> 4, r = lane & 15;
  // XCD-compact bijective remap: 512 blocks -> 8 rectangles of 2tn x 32tm.
  const int bid = blockIdx.x + 8 * blockIdx.y;
  const int xcd = bid & 7, idx = bid >> 3;           // idx 0..63
  const int tn = (xcd & 3) * 2 + (idx & 1);
  const int tm = ((xcd >> 2) << 5) + (idx >> 1);

  f32x4 acc[4][2] = {};

  const char* Ab = (const char*)(A + (size_t)tm * 64 * 1024);
  const char* Bb = (const char*)(Bm + (size_t)tn * 128 * 1024);

  auto stage = [&](int t, int buf) {
    char* AsD = (char*)SMEM + buf * 24576;
    char* BsD = AsD + 8192;
#pragma unroll
    for (int i = 0; i < 2; ++i) {              // A: 64 rows x 128B = 8KB
      const int L = (i * 256 + tid) * 16;
      const int row = L >> 7;
      const int colb = (L & 127) ^ ((row & 7) << 4);
      gload_lds16(Ab + (size_t)row * 2048 + t * 128 + colb, AsD + L);
    }
#pragma unroll
    for (int i = 0; i < 4; ++i) {              // B: 128 rows x 128B = 16KB
      const int L = (i * 256 + tid) * 16;
      const int row = L >> 7;
      const int colb = (L & 127) ^ ((row & 7) << 4);
      gload_lds16(Bb + (size_t)row * 2048 + t * 128 + colb, BsD + L);
    }
  };

  stage(0, 0);
  for (int t = 0; t < 16; ++t) {
    if (t < 15) {
      stage(t + 1, (t + 1) & 1);                       // 6 loads in flight
      asm volatile("s_waitcnt vmcnt(6)" ::: "memory"); // tile t landed
    } else {
      asm volatile("s_waitcnt vmcnt(0)" ::: "memory");
    }
    __builtin_amdgcn_s_barrier();
    __builtin_amdgcn_sched_barrier(0);
    const char* AsB = (const char*)SMEM + (t & 1) * 24576;
    const char* BsB = AsB + 8192;
#pragma unroll
    for (int kk = 0; kk < 2; ++kk) {
      bf16x8 a[4], b[2];
#pragma unroll
      for (int m = 0; m < 4; ++m) {
        const int rowA = m * 16 + r;
        const int kbyt = (kk * 64 + g * 16) ^ ((rowA & 7) << 4);
        a[m] = *(const bf16x8*)(AsB + rowA * 128 + kbyt);
      }
#pragma unroll
      for (int n = 0; n < 2; ++n) {
        const int rowB = w * 32 + n * 16 + r;
        const int kbyt = (kk * 64 + g * 16) ^ ((rowB & 7) << 4);
        b[n] = *(const bf16x8*)(BsB + rowB * 128 + kbyt);
      }
      __builtin_amdgcn_s_setprio(1);
#pragma unroll
      for (int m = 0; m < 4; ++m)
#pragma unroll
        for (int n = 0; n < 2; ++n)
          acc[m][n] = __builtin_amdgcn_mfma_f32_16x16x32_bf16(a[m], b[n], acc[m][n], 0, 0, 0);
      __builtin_amdgcn_s_setprio(0);
    }
    __builtin_amdgcn_sched_barrier(0);
    __builtin_amdgcn_s_barrier();              // all reads of buf(t&1) done
  }

  const int mrow0 = tm * 64;
  const int ncol0 = tn * 128 + w * 32;
#pragma unroll
  for (int m = 0; m < 4; ++m)
#pragma unroll
    for (int n = 0; n < 2; ++n) {
      const int nc = ncol0 + n * 16 + r;
#pragma unroll
      for (int j = 0; j < 4; ++j) {
        const int mr = mrow0 + m * 16 + g * 4 + j;
        outf[(size_t)mr * 1024 + nc] = acc[m][n][j];
      }
    }
}

// ---------------------------------------------------------------------------
// Flash attention, causal, 32x32 MFMA, swapped-operand QK^T (S^T = K·Q^T),
// fixed-reference softmax (p = exp2(s)), P-frags via cvt_pk+permlane32_swap.
// Block = 4 waves x 32 q = 128 q. KVBLK=128/phase, LDS double-buffered,
// stage(t+1) then vmcnt(8) + raw barriers. Zigzag chunk map balances CUs.
// psum accumulated via 4-way partial trees (no serial FP chain).
// ---------------------------------------------------------------------------
__global__ __launch_bounds__(256, 2)
void attn_fwd(const u16* __restrict__ qb, const u16* __restrict__ kb,
              const u16* __restrict__ vb, u16* __restrict__ yb) {
  __shared__ __attribute__((aligned(16))) u16 Ks[2][128 * 64]; // [k][d] swz
  __shared__ __attribute__((aligned(16))) u16 Vs[2][64 * 128]; // [d][k] swz
  __shared__ __attribute__((aligned(16))) float Linv[4][32];
  const int tid = threadIdx.x;
  const int lane = tid & 63;
  const int w = tid >> 6;
  const int hi = lane >> 5;
  const int q5 = lane & 31;
  const int hi4 = hi * 4;
  const int bh = blockIdx.x;
  const int bb = bh >> 4, h = bh & 15;
  const int base = (blockIdx.y + bh) & 15;
  const int a = (base < 8) ? 2 * base : 31 - 2 * base;   // zigzag, 0..15
  const int qb0 = a * 128;
  const int qw = qb0 + w * 32;
  const int qg = qw + q5;

  const char* Kb = (const char*)(kb + (size_t)bh * (2048 * 64));
  const char* Vb = (const char*)(vb + (size_t)bh * (64 * 2048));
  const u16* Q = qb + (size_t)bh * (2048 * 64);

  bf16x8 qf[4];
#pragma unroll
  for (int f = 0; f < 4; ++f)
    qf[f] = *(const bf16x8*)(&Q[(size_t)qg * 64 + f * 16 + hi * 8]);

  f32x16 o0 = {}, o1 = {};
  float ps0 = 0.f, ps1 = 0.f, ps2 = 0.f, ps3 = 0.f;   // psum partials

  const int nph = a + 1;                 // phases of 128 k
  const int swzK = (q5 & 7) << 4;
  const int swzV = (q5 & 15) << 4;

  auto stage = [&](int p, int buf) {
#pragma unroll
    for (int i = 0; i < 4; ++i) {        // K: 128 rows x 128B = 16KB
      const int L = (i * 256 + tid) * 16;
      const int row = L >> 7;
      const int colb = (L & 127) ^ ((row & 7) << 4);
      gload_lds16(Kb + ((size_t)p * 128 + row) * 128 + colb, (char*)Ks[buf] + L);
    }
#pragma unroll
    for (int i = 0; i < 4; ++i) {        // V: 64 rows x 256B = 16KB
      const int L = (i * 256 + tid) * 16;
      const int row = L >> 8;
      const int colb = (L & 255) ^ ((row & 15) << 4);
      gload_lds16(Vb + (size_t)row * 4096 + (size_t)p * 256 + colb, (char*)Vs[buf] + L);
    }
  };

  auto compute = [&](int p, const char* KsB, const char* VsB) {
#pragma unroll
    for (int hh = 0; hh < 4; ++hh) {     // 32-k halves
      const int kh = p * 128 + hh * 32;
      if (kh <= qw + 31) {               // wave-uniform causal skip
        f32x16 s = {};
        __builtin_amdgcn_s_setprio(1);
#pragma unroll
        for (int f = 0; f < 4; ++f) {
          bf16x8 ka = *(const bf16x8*)(KsB + (hh * 32 + q5) * 128 + ((f * 32 + hi * 16) ^ swzK));
          s = __builtin_amdgcn_mfma_f32_32x32x16_bf16(ka, qf[f], s, 0, 0, 0);
        }
        __builtin_amdgcn_s_setprio(0);

        float pv[16];
        if (kh + 31 > qw) {              // diagonal-clipping half: mask
#pragma unroll
          for (int i = 0; i < 16; ++i) {
            const int kl = (i & 3) + 8 * (i >> 2) + hi4;
            float e = hexp2(s[i]);
            pv[i] = (kh + kl <= qg) ? e : 0.0f;
          }
        } else {
#pragma unroll
          for (int i = 0; i < 16; ++i)
            pv[i] = hexp2(s[i]);
        }
#pragma unroll
        for (int i = 0; i < 16; i += 4) {   // 4-way partial tree (no chain)
          ps0 += pv[i];
          ps1 += pv[i + 1];
          ps2 += pv[i + 2];
          ps3 += pv[i + 3];
        }

        bf16x8 pf0 = mkPfrag<0>(pv);
        bf16x8 pf1 = mkPfrag<1>(pv);

        __builtin_amdgcn_s_setprio(1);
#pragma unroll
        for (int c = 0; c < 2; ++c) {    // 16-k chunks of this half
          const int cc = hh * 2 + c;
          const int cb = cc * 32 + hi * 16;
          bf16x8 v0f = *(const bf16x8*)(VsB + q5 * 256 + (cb ^ swzV));
          bf16x8 v1f = *(const bf16x8*)(VsB + (32 + q5) * 256 + (cb ^ swzV));
          const bf16x8 pf = c ? pf1 : pf0;
          o0 = __builtin_amdgcn_mfma_f32_32x32x16_bf16(pf, v0f, o0, 0, 0, 0);
          o1 = __builtin_amdgcn_mfma_f32_32x32x16_bf16(pf, v1f, o1, 0, 0, 0);
        }
        __builtin_amdgcn_s_setprio(0);
      }
    }
  };

  stage(0, 0);
  for (int t = 0; t < nph; ++t) {
    const int pn = (t + 1 < nph) ? t + 1 : 0;
    stage(pn, (t + 1) & 1);                           // 8 loads in flight
    asm volatile("s_waitcnt vmcnt(8)" ::: "memory");  // phase t's loads done
    __builtin_amdgcn_s_barrier();
    __builtin_amdgcn_sched_barrier(0);
    compute(t, (const char*)Ks[t & 1], (const char*)Vs[t & 1]);
    __builtin_amdgcn_sched_barrier(0);
    __builtin_amdgcn_s_barrier();                     // all done with buf t&1
  }

  float psum = (ps0 + ps1) + (ps2 + ps3);
  const float tot = psum + __shfl_xor(psum, 32);
  if (lane < 32) Linv[w][q5] = 1.0f / tot;
  asm volatile("s_waitcnt lgkmcnt(0)" ::: "memory");
  __builtin_amdgcn_sched_barrier(0);
  f32x4 lv[4];
#pragma unroll
  for (int r2 = 0; r2 < 4; ++r2)
    lv[r2] = *(const f32x4*)(&Linv[w][r2 * 8 + hi4]);

#pragma unroll
  for (int reg = 0; reg < 16; ++reg) {
    const int r4 = reg & 3, r2 = reg >> 2;
    const float li = lv[r2][r4];
    const int trow = qw + r4 + 8 * r2 + hi4;
    const size_t bpos = ((size_t)(bb * 2048 + trow)) * 1024 + h * 64 + q5;
    yb[bpos]      = f2bf(o0[reg] * li);
    yb[bpos + 32] = f2bf(o1[reg] * li);
  }
}

// ---------------------------------------------------------------------------
// Workspace layout (48 MB):
//  0MB xb | 8MB wqkvb | 14MB wprojb | 16MB q | 24MB k | 32MB v | 40MB y
// ---------------------------------------------------------------------------
extern "C" void kernel_launch(void* const* d_in, const int* in_sizes, int n_in,
                              void* d_out, int out_size, void* d_ws, size_t ws_size,
                              hipStream_t stream) {
  const float* x     = (const float*)d_in[0];
  const float* wqkv  = (const float*)d_in[1];
  const float* wproj = (const float*)d_in[2];
  float* out = (float*)d_out;
  char* ws = (char*)d_ws;
  u16* xb     = (u16*)(ws + (size_t)(0u  << 20));
  u16* wqkvb  = (u16*)(ws + (size_t)(8u  << 20));
  u16* wprojb = (u16*)(ws + (size_t)(14u << 20));
  u16* qb     = (u16*)(ws + (size_t)(16u << 20));
  u16* kb     = (u16*)(ws + (size_t)(24u << 20));
  u16* vb     = (u16*)(ws + (size_t)(32u << 20));
  u16* yb     = (u16*)(ws + (size_t)(40u << 20));

  cast_all<<<8192, 256, 0, stream>>>(x, wqkv, wproj, xb, wqkvb, wprojb);

  gemm_qkv<<<dim3(24, 32), 256, 0, stream>>>(xb, wqkvb, qb, kb, vb);
  attn_fwd<<<dim3(32, 16), 256, 0, stream>>>(qb, kb, vb, yb);
  gemm_out<<<dim3(8, 64), 256, 0, stream>>>(yb, wprojb, out);
}

// Round 11
// 86.737 us; speedup vs baseline: 1.0270x; 1.0270x over previous
//
#include <hip/hip_runtime.h>
#include <stdint.h>

// Problem constants: B=2, T=2048, C=1024, H=16, D=64
// GEMM1: [4096,1024] x [3072,1024]^T -> q,k,v  (128^2, 3 blocks/CU,
//        XCD-compact, coalesced LDS-transpose epilogue)
// attn : 32 heads, causal, T=2048, D=64
// GEMM2: [4096,1024] x [1024,1024]^T -> out (fp32), prefetch-dbuf, XCD-compact

typedef unsigned short u16;
typedef __bf16 bf16_t;
typedef bf16_t bf16x8 __attribute__((ext_vector_type(8)));
typedef float f32x4 __attribute__((ext_vector_type(4)));
typedef float f32x16 __attribute__((ext_vector_type(16)));

__device__ __forceinline__ u16 f2bf(float f) {
  return __builtin_bit_cast(u16, (bf16_t)f);   // RNE
}

__device__ __forceinline__ float hexp2(float x) {   // raw v_exp_f32 (log2 domain)
  float r;
  asm("v_exp_f32 %0, %1" : "=v"(r) : "v"(x));
  return r;
}
__device__ __forceinline__ uint32_t cvtpk(float lo, float hi) {
  uint32_t d;
  asm("v_cvt_pk_bf16_f32 %0, %1, %2" : "=v"(d) : "v"(lo), "v"(hi));
  return d;
}
__device__ __forceinline__ void plswap(uint32_t& a, uint32_t& b) {
  asm("v_permlane32_swap_b32 %0, %1" : "+v"(a), "+v"(b));
}

// PV A-fragment (k-chunk CC of 16 within a 32-k half) from this lane's 16 S^T
// values (k_local = (reg&3) + 8*(reg>>2) + 4*hi).
template<int CC>
__device__ __forceinline__ bf16x8 mkPfrag(const float* p) {
  uint32_t A1 = cvtpk(p[8 * CC + 0], p[8 * CC + 1]);
  uint32_t A2 = cvtpk(p[8 * CC + 2], p[8 * CC + 3]);
  uint32_t B1 = cvtpk(p[8 * CC + 4], p[8 * CC + 5]);
  uint32_t B2 = cvtpk(p[8 * CC + 6], p[8 * CC + 7]);
  plswap(A1, B1);
  plswap(A2, B2);
  union { uint32_t u[4]; bf16x8 v; } r;
  r.u[0] = A1; r.u[1] = A2; r.u[2] = B1; r.u[3] = B2;
  return r.v;
}

// global -> LDS direct copy, 16B per lane (linear LDS dest; swizzle on source).
__device__ __forceinline__ void gload_lds16(const void* g, void* l) {
  __builtin_amdgcn_global_load_lds(
      (const __attribute__((address_space(1))) uint32_t*)(uint64_t)g,
      (__attribute__((address_space(3))) uint32_t*)(uint32_t)(uint64_t)l,
      16, 0, 0);
}

// Fused bf16 cast of x, w_qkv, w_proj.
__global__ void cast_all(const float* __restrict__ x, const float* __restrict__ wq,
                         const float* __restrict__ wp, u16* __restrict__ xb,
                         u16* __restrict__ wqb, u16* __restrict__ wpb) {
  int i = blockIdx.x * blockDim.x + threadIdx.x;
  const float* s; u16* d; int off;
  if (i < 1048576)            { s = x;  d = xb;  off = i; }
  else if (i < 1048576 + 786432) { s = wq; d = wqb; off = i - 1048576; }
  else                        { s = wp; d = wpb; off = i - (1048576 + 786432); }
  float4 f = reinterpret_cast<const float4*>(s)[off];
  ushort4 o;
  o.x = f2bf(f.x); o.y = f2bf(f.y); o.z = f2bf(f.z); o.w = f2bf(f.w);
  reinterpret_cast<ushort4*>(d)[off] = o;
}

// ---------------------------------------------------------------------------
// GEMM1: 128x128 tile, BK=64, 256 threads (2x2 waves, 64x64/wave), 32KB LDS
// -> 3 blocks/CU (single-buffer loop: r10 A/B showed the 3rd resident block
// beats counted-vmcnt dbuf at this structure). XCD-compact remap.
// Epilogue (kept from r10): per-wave LDS transpose -> coalesced stores.
// ---------------------------------------------------------------------------
__global__ void gemm_qkv(const u16* __restrict__ A, const u16* __restrict__ Bm,
                         u16* __restrict__ qb, u16* __restrict__ kb,
                         u16* __restrict__ vb) {
  __shared__ __attribute__((aligned(16))) u16 SMEM[16384];   // 32KB
  const int tid = threadIdx.x;
  const int lane = tid & 63;
  const int w = tid >> 6;
  const int wr = w >> 1, wc = w & 1;
  const int g = lane >> 4, r = lane & 15;
  // XCD-compact bijective remap: 768 blocks -> 8 rectangles of 12tn x 8tm.
  const int bid = blockIdx.x + 24 * blockIdx.y;
  const int xcd = bid & 7, idx = bid >> 3;           // idx 0..95
  const int tn = (xcd & 1) * 12 + (idx % 12);
  const int tm = (xcd >> 1) * 8 + (idx / 12);

  f32x4 acc[4][4] = {};

  const char* Ab = (const char*)(A + (size_t)tm * 128 * 1024);
  const char* Bb = (const char*)(Bm + (size_t)tn * 128 * 1024);
  char* AsB = (char*)SMEM;
  char* BsB = AsB + 16384;

  for (int k0 = 0; k0 < 1024; k0 += 64) {
#pragma unroll
    for (int i = 0; i < 4; ++i) {
      const int L = (i * 256 + tid) * 16;
      const int row = L >> 7;
      const int colb = (L & 127) ^ ((row & 7) << 4);
      gload_lds16(Ab + (size_t)row * 2048 + k0 * 2 + colb, AsB + L);
      gload_lds16(Bb + (size_t)row * 2048 + k0 * 2 + colb, BsB + L);
    }
    __syncthreads();
#pragma unroll
    for (int kk = 0; kk < 2; ++kk) {
      bf16x8 a[4], b[4];
#pragma unroll
      for (int m = 0; m < 4; ++m) {
        const int rowA = wr * 64 + m * 16 + r;
        const int kbyt = (kk * 64 + g * 16) ^ ((rowA & 7) << 4);
        a[m] = *(const bf16x8*)(AsB + rowA * 128 + kbyt);
      }
#pragma unroll
      for (int n = 0; n < 4; ++n) {
        const int rowB = wc * 64 + n * 16 + r;
        const int kbyt = (kk * 64 + g * 16) ^ ((rowB & 7) << 4);
        b[n] = *(const bf16x8*)(BsB + rowB * 128 + kbyt);
      }
      __builtin_amdgcn_s_setprio(1);
#pragma unroll
      for (int m = 0; m < 4; ++m)
#pragma unroll
        for (int n = 0; n < 4; ++n)
          acc[m][n] = __builtin_amdgcn_mfma_f32_16x16x32_bf16(a[m], b[n], acc[m][n], 0, 0, 0);
      __builtin_amdgcn_s_setprio(0);
    }
    __syncthreads();   // final iter: also fences SMEM for epilogue reuse
  }

  // ---- epilogue: per-wave 8KB LDS transpose buffers (reuse SMEM) ----------
  const int mrow0 = tm * 128 + wr * 64;
  const int ncol0 = tn * 128 + wc * 64;
  const int sel = (tn * 128) >> 10;
  u16* Wb = SMEM + w * 4096;                   // 8KB per wave (u16 index)

  if (sel < 2) {
    // q/k: build W[t][d] (64 x 64, 128B rows, 16B-granule XOR swizzle),
    // then store full 128B t-rows (8 lanes x 16B, coalesced).
    const float qscl = (sel == 0) ? 0.18033688f : 1.0f;  // 0.125*log2(e)
#pragma unroll
    for (int m = 0; m < 4; ++m)
#pragma unroll
      for (int n = 0; n < 4; ++n)
#pragma unroll
        for (int j = 0; j < 4; ++j) {
          const int tl = m * 16 + g * 4 + j;
          const int d = n * 16 + r;
          *(u16*)((char*)Wb + tl * 128 + ((d * 2) ^ ((tl & 7) << 4))) =
              f2bf(acc[m][n][j] * qscl);
        }
    asm volatile("s_waitcnt lgkmcnt(0)" ::: "memory");   // wave-local
    __builtin_amdgcn_sched_barrier(0);
    u16* dst = (sel == 0) ? qb : kb;
    const int h = (ncol0 & 1023) >> 6;
    const int bb = mrow0 >> 11, t0 = mrow0 & 2047;
    u16* drow = dst + ((size_t)(bb * 16 + h) * 2048 + t0) * 64;
#pragma unroll
    for (int it = 0; it < 8; ++it) {
      const int tl = it * 8 + (lane >> 3);
      const int cb = (lane & 7) * 16;
      const char* src = (char*)Wb + tl * 128 + (cb ^ ((tl & 7) << 4));
      *(uint4*)((char*)(drow + (size_t)tl * 64) + cb) = *(const uint4*)src;
    }
  } else {
    // v: [b,h,d,t] via W[d][t] transpose (b64 packed writes).
#pragma unroll
    for (int m = 0; m < 4; ++m)
#pragma unroll
      for (int n = 0; n < 4; ++n) {
        const int dl = n * 16 + r;
        uint32_t lo = cvtpk(acc[m][n][0], acc[m][n][1]);
        uint32_t hi2 = cvtpk(acc[m][n][2], acc[m][n][3]);
        char* p = (char*)Wb + dl * 128 + ((m * 32 + g * 8) ^ ((dl & 7) << 4));
        *(uint64_t*)p = ((uint64_t)hi2 << 32) | lo;
      }
    asm volatile("s_waitcnt lgkmcnt(0)" ::: "memory");   // wave-local
    __builtin_amdgcn_sched_barrier(0);
    const int hh = (ncol0 - 2048) >> 6;
    const int t0 = mrow0 & 2047;
    const int bb2 = mrow0 >> 11;
    u16* vdst = vb + ((size_t)(bb2 * 16 + hh) * 64) * 2048 + t0;
#pragma unroll
    for (int rd = 0; rd < 8; ++rd) {
      const int dl = rd * 8 + (lane >> 3);
      const int tb = lane & 7;
      const char* src = (char*)Wb + dl * 128 + ((tb ^ (dl & 7)) << 4);
      *(uint4*)(vdst + (size_t)dl * 2048 + tb * 8) = *(const uint4*)src;
    }
  }
}

// ---------------------------------------------------------------------------
// GEMM2: 64x128 tile, BK=64, 256 threads (1x4 waves, 64x32/wave), fp32 out.
// Prefetch double-buffer, counted vmcnt(6) + raw s_barrier.
// XCD-compact remap: XCD owns 2(tn) x 32(tm).
// ---------------------------------------------------------------------------
__global__ void gemm_out(const u16* __restrict__ A, const u16* __restrict__ Bm,
                         float* __restrict__ outf) {
  __shared__ __attribute__((aligned(16))) u16 SMEM[24576];   // 2 x 24KB
  const int tid = threadIdx.x;
  const int lane = tid & 63;
  const int w = tid >> 6;
  const int g = lane >> 4, r = lane & 15;
  // XCD-compact bijective remap: 512 blocks -> 8 rectangles of 2tn x 32tm.
  const int bid = blockIdx.x + 8 * blockIdx.y;
  const int xcd = bid & 7, idx = bid >> 3;           // idx 0..63
  const int tn = (xcd & 3) * 2 + (idx & 1);
  const int tm = ((xcd >> 2) << 5) + (idx >> 1);

  f32x4 acc[4][2] = {};

  const char* Ab = (const char*)(A + (size_t)tm * 64 * 1024);
  const char* Bb = (const char*)(Bm + (size_t)tn * 128 * 1024);

  auto stage = [&](int t, int buf) {
    char* AsD = (char*)SMEM + buf * 24576;
    char* BsD = AsD + 8192;
#pragma unroll
    for (int i = 0; i < 2; ++i) {              // A: 64 rows x 128B = 8KB
      const int L = (i * 256 + tid) * 16;
      const int row = L >> 7;
      const int colb = (L & 127) ^ ((row & 7) << 4);
      gload_lds16(Ab + (size_t)row * 2048 + t * 128 + colb, AsD + L);
    }
#pragma unroll
    for (int i = 0; i < 4; ++i) {              // B: 128 rows x 128B = 16KB
      const int L = (i * 256 + tid) * 16;
      const int row = L >> 7;
      const int colb = (L & 127) ^ ((row & 7) << 4);
      gload_lds16(Bb + (size_t)row * 2048 + t * 128 + colb, BsD + L);
    }
  };

  stage(0, 0);
  for (int t = 0; t < 16; ++t) {
    if (t < 15) {
      stage(t + 1, (t + 1) & 1);                       // 6 loads in flight
      asm volatile("s_waitcnt vmcnt(6)" ::: "memory"); // tile t landed
    } else {
      asm volatile("s_waitcnt vmcnt(0)" ::: "memory");
    }
    __builtin_amdgcn_s_barrier();
    __builtin_amdgcn_sched_barrier(0);
    const char* AsB = (const char*)SMEM + (t & 1) * 24576;
    const char* BsB = AsB + 8192;
#pragma unroll
    for (int kk = 0; kk < 2; ++kk) {
      bf16x8 a[4], b[2];
#pragma unroll
      for (int m = 0; m < 4; ++m) {
        const int rowA = m * 16 + r;
        const int kbyt = (kk * 64 + g * 16) ^ ((rowA & 7) << 4);
        a[m] = *(const bf16x8*)(AsB + rowA * 128 + kbyt);
      }
#pragma unroll
      for (int n = 0; n < 2; ++n) {
        const int rowB = w * 32 + n * 16 + r;
        const int kbyt = (kk * 64 + g * 16) ^ ((rowB & 7) << 4);
        b[n] = *(const bf16x8*)(BsB + rowB * 128 + kbyt);
      }
      __builtin_amdgcn_s_setprio(1);
#pragma unroll
      for (int m = 0; m < 4; ++m)
#pragma unroll
        for (int n = 0; n < 2; ++n)
          acc[m][n] = __builtin_amdgcn_mfma_f32_16x16x32_bf16(a[m], b[n], acc[m][n], 0, 0, 0);
      __builtin_amdgcn_s_setprio(0);
    }
    __builtin_amdgcn_sched_barrier(0);
    __builtin_amdgcn_s_barrier();              // all reads of buf(t&1) done
  }

  const int mrow0 = tm * 64;
  const int ncol0 = tn * 128 + w * 32;
#pragma unroll
  for (int m = 0; m < 4; ++m)
#pragma unroll
    for (int n = 0; n < 2; ++n) {
      const int nc = ncol0 + n * 16 + r;
#pragma unroll
      for (int j = 0; j < 4; ++j) {
        const int mr = mrow0 + m * 16 + g * 4 + j;
        outf[(size_t)mr * 1024 + nc] = acc[m][n][j];
      }
    }
}

// ---------------------------------------------------------------------------
// Flash attention, causal, 32x32 MFMA, swapped-operand QK^T (S^T = K·Q^T),
// fixed-reference softmax (p = exp2(s)), P-frags via cvt_pk+permlane32_swap.
// Block = 4 waves x 32 q = 128 q. KVBLK=128/phase, LDS double-buffered,
// stage(t+1) then vmcnt(8) + raw barriers. Zigzag chunk map balances CUs.
// psum accumulated via 4-way partial trees (no serial FP chain).
// ---------------------------------------------------------------------------
__global__ __launch_bounds__(256, 2)
void attn_fwd(const u16* __restrict__ qb, const u16* __restrict__ kb,
              const u16* __restrict__ vb, u16* __restrict__ yb) {
  __shared__ __attribute__((aligned(16))) u16 Ks[2][128 * 64]; // [k][d] swz
  __shared__ __attribute__((aligned(16))) u16 Vs[2][64 * 128]; // [d][k] swz
  __shared__ __attribute__((aligned(16))) float Linv[4][32];
  const int tid = threadIdx.x;
  const int lane = tid & 63;
  const int w = tid >> 6;
  const int hi = lane >> 5;
  const int q5 = lane & 31;
  const int hi4 = hi * 4;
  const int bh = blockIdx.x;
  const int bb = bh >> 4, h = bh & 15;
  const int base = (blockIdx.y + bh) & 15;
  const int a = (base < 8) ? 2 * base : 31 - 2 * base;   // zigzag, 0..15
  const int qb0 = a * 128;
  const int qw = qb0 + w * 32;
  const int qg = qw + q5;

  const char* Kb = (const char*)(kb + (size_t)bh * (2048 * 64));
  const char* Vb = (const char*)(vb + (size_t)bh * (64 * 2048));
  const u16* Q = qb + (size_t)bh * (2048 * 64);

  bf16x8 qf[4];
#pragma unroll
  for (int f = 0; f < 4; ++f)
    qf[f] = *(const bf16x8*)(&Q[(size_t)qg * 64 + f * 16 + hi * 8]);

  f32x16 o0 = {}, o1 = {};
  float ps0 = 0.f, ps1 = 0.f, ps2 = 0.f, ps3 = 0.f;   // psum partials

  const int nph = a + 1;                 // phases of 128 k
  const int swzK = (q5 & 7) << 4;
  const int swzV = (q5 & 15) << 4;

  auto stage = [&](int p, int buf) {
#pragma unroll
    for (int i = 0; i < 4; ++i) {        // K: 128 rows x 128B = 16KB
      const int L = (i * 256 + tid) * 16;
      const int row = L >> 7;
      const int colb = (L & 127) ^ ((row & 7) << 4);
      gload_lds16(Kb + ((size_t)p * 128 + row) * 128 + colb, (char*)Ks[buf] + L);
    }
#pragma unroll
    for (int i = 0; i < 4; ++i) {        // V: 64 rows x 256B = 16KB
      const int L = (i * 256 + tid) * 16;
      const int row = L >> 8;
      const int colb = (L & 255) ^ ((row & 15) << 4);
      gload_lds16(Vb + (size_t)row * 4096 + (size_t)p * 256 + colb, (char*)Vs[buf] + L);
    }
  };

  auto compute = [&](int p, const char* KsB, const char* VsB) {
#pragma unroll
    for (int hh = 0; hh < 4; ++hh) {     // 32-k halves
      const int kh = p * 128 + hh * 32;
      if (kh <= qw + 31) {               // wave-uniform causal skip
        f32x16 s = {};
        __builtin_amdgcn_s_setprio(1);
#pragma unroll
        for (int f = 0; f < 4; ++f) {
          bf16x8 ka = *(const bf16x8*)(KsB + (hh * 32 + q5) * 128 + ((f * 32 + hi * 16) ^ swzK));
          s = __builtin_amdgcn_mfma_f32_32x32x16_bf16(ka, qf[f], s, 0, 0, 0);
        }
        __builtin_amdgcn_s_setprio(0);

        float pv[16];
        if (kh + 31 > qw) {              // diagonal-clipping half: mask
#pragma unroll
          for (int i = 0; i < 16; ++i) {
            const int kl = (i & 3) + 8 * (i >> 2) + hi4;
            float e = hexp2(s[i]);
            pv[i] = (kh + kl <= qg) ? e : 0.0f;
          }
        } else {
#pragma unroll
          for (int i = 0; i < 16; ++i)
            pv[i] = hexp2(s[i]);
        }
#pragma unroll
        for (int i = 0; i < 16; i += 4) {   // 4-way partial tree (no chain)
          ps0 += pv[i];
          ps1 += pv[i + 1];
          ps2 += pv[i + 2];
          ps3 += pv[i + 3];
        }

        bf16x8 pf0 = mkPfrag<0>(pv);
        bf16x8 pf1 = mkPfrag<1>(pv);

        __builtin_amdgcn_s_setprio(1);
#pragma unroll
        for (int c = 0; c < 2; ++c) {    // 16-k chunks of this half
          const int cc = hh * 2 + c;
          const int cb = cc * 32 + hi * 16;
          bf16x8 v0f = *(const bf16x8*)(VsB + q5 * 256 + (cb ^ swzV));
          bf16x8 v1f = *(const bf16x8*)(VsB + (32 + q5) * 256 + (cb ^ swzV));
          const bf16x8 pf = c ? pf1 : pf0;
          o0 = __builtin_amdgcn_mfma_f32_32x32x16_bf16(pf, v0f, o0, 0, 0, 0);
          o1 = __builtin_amdgcn_mfma_f32_32x32x16_bf16(pf, v1f, o1, 0, 0, 0);
        }
        __builtin_amdgcn_s_setprio(0);
      }
    }
  };

  stage(0, 0);
  for (int t = 0; t < nph; ++t) {
    const int pn = (t + 1 < nph) ? t + 1 : 0;
    stage(pn, (t + 1) & 1);                           // 8 loads in flight
    asm volatile("s_waitcnt vmcnt(8)" ::: "memory");  // phase t's loads done
    __builtin_amdgcn_s_barrier();
    __builtin_amdgcn_sched_barrier(0);
    compute(t, (const char*)Ks[t & 1], (const char*)Vs[t & 1]);
    __builtin_amdgcn_sched_barrier(0);
    __builtin_amdgcn_s_barrier();                     // all done with buf t&1
  }

  float psum = (ps0 + ps1) + (ps2 + ps3);
  const float tot = psum + __shfl_xor(psum, 32);
  if (lane < 32) Linv[w][q5] = 1.0f / tot;
  asm volatile("s_waitcnt lgkmcnt(0)" ::: "memory");
  __builtin_amdgcn_sched_barrier(0);
  f32x4 lv[4];
#pragma unroll
  for (int r2 = 0; r2 < 4; ++r2)
    lv[r2] = *(const f32x4*)(&Linv[w][r2 * 8 + hi4]);

#pragma unroll
  for (int reg = 0; reg < 16; ++reg) {
    const int r4 = reg & 3, r2 = reg >> 2;
    const float li = lv[r2][r4];
    const int trow = qw + r4 + 8 * r2 + hi4;
    const size_t bpos = ((size_t)(bb * 2048 + trow)) * 1024 + h * 64 + q5;
    yb[bpos]      = f2bf(o0[reg] * li);
    yb[bpos + 32] = f2bf(o1[reg] * li);
  }
}

// ---------------------------------------------------------------------------
// Workspace layout (48 MB):
//  0MB xb | 8MB wqkvb | 14MB wprojb | 16MB q | 24MB k | 32MB v | 40MB y
// ---------------------------------------------------------------------------
extern "C" void kernel_launch(void* const* d_in, const int* in_sizes, int n_in,
                              void* d_out, int out_size, void* d_ws, size_t ws_size,
                              hipStream_t stream) {
  const float* x     = (const float*)d_in[0];
  const float* wqkv  = (const float*)d_in[1];
  const float* wproj = (const float*)d_in[2];
  float* out = (float*)d_out;
  char* ws = (char*)d_ws;
  u16* xb     = (u16*)(ws + (size_t)(0u  << 20));
  u16* wqkvb  = (u16*)(ws + (size_t)(8u  << 20));
  u16* wprojb = (u16*)(ws + (size_t)(14u << 20));
  u16* qb     = (u16*)(ws + (size_t)(16u << 20));
  u16* kb     = (u16*)(ws + (size_t)(24u << 20));
  u16* vb     = (u16*)(ws + (size_t)(32u << 20));
  u16* yb     = (u16*)(ws + (size_t)(40u << 20));

  cast_all<<<8192, 256, 0, stream>>>(x, wqkv, wproj, xb, wqkvb, wprojb);

  gemm_qkv<<<dim3(24, 32), 256, 0, stream>>>(xb, wqkvb, qb, kb, vb);
  attn_fwd<<<dim3(32, 16), 256, 0, stream>>>(qb, kb, vb, yb);
  gemm_out<<<dim3(8, 64), 256, 0, stream>>>(yb, wprojb, out);
}